// Round 1
// baseline (310.303 us; speedup 1.0000x reference)
//
#include <hip/hip_runtime.h>
#include <hip/hip_bf16.h>

// Problem constants (from reference)
#define BATCH   16384
#define DENSE_D 512
#define HIDDEN1 512
#define HIDDEN2 256
#define EMB_D   64
#define NFEAT   7
#define NROWS   9              // dense + hist + 7 feats
#define NPAIRS  36             // upper triangle k=1 of 9x9
#define COMB    (EMB_D + NPAIRS)   // 100
#define PROJ    128
#define C_CAMP  1000
#define C_FEAT  316
#define NQ_FEAT 317

// ---------------------------------------------------------------------------
// GEMM: C[M][N] = act(A[M][K] @ W[N][K]^T + bias[N]);  A,W row-major (K-contig)
// Tile 64x64, BK=16, 256 threads, 4x4 accum per thread. fp32.
// LDS stored K-major (As[k][row]) so inner-loop reads are broadcast/2-way.
// ---------------------------------------------------------------------------
template<bool RELU>
__global__ __launch_bounds__(256)
void gemm_bias_act(const float* __restrict__ A, const float* __restrict__ W,
                   const float* __restrict__ bias, float* __restrict__ C,
                   int M, int N, int K)
{
    __shared__ float As[16][64];
    __shared__ float Ws[16][64];
    const int tid = threadIdx.x;
    const int tx = tid & 15;        // N direction
    const int ty = tid >> 4;        // M direction
    const int row0 = blockIdx.x * 64;
    const int col0 = blockIdx.y * 64;

    float acc[4][4] = {};

    const int lr  = tid >> 2;        // 0..63 load row
    const int lc4 = (tid & 3) * 4;   // 0,4,8,12 load k-offset

    for (int k0 = 0; k0 < K; k0 += 16) {
        const float4 av = *reinterpret_cast<const float4*>(
            &A[(size_t)(row0 + lr) * K + k0 + lc4]);
        const float4 wv = *reinterpret_cast<const float4*>(
            &W[(size_t)(col0 + lr) * K + k0 + lc4]);
        As[lc4 + 0][lr] = av.x; As[lc4 + 1][lr] = av.y;
        As[lc4 + 2][lr] = av.z; As[lc4 + 3][lr] = av.w;
        Ws[lc4 + 0][lr] = wv.x; Ws[lc4 + 1][lr] = wv.y;
        Ws[lc4 + 2][lr] = wv.z; Ws[lc4 + 3][lr] = wv.w;
        __syncthreads();

        #pragma unroll
        for (int k = 0; k < 16; ++k) {
            float a[4], w[4];
            #pragma unroll
            for (int i = 0; i < 4; ++i) a[i] = As[k][ty * 4 + i];
            #pragma unroll
            for (int j = 0; j < 4; ++j) w[j] = Ws[k][tx * 4 + j];
            #pragma unroll
            for (int i = 0; i < 4; ++i)
                #pragma unroll
                for (int j = 0; j < 4; ++j)
                    acc[i][j] += a[i] * w[j];
        }
        __syncthreads();
    }

    const int c0 = col0 + tx * 4;
    float4 bv = *reinterpret_cast<const float4*>(&bias[c0]);
    #pragma unroll
    for (int i = 0; i < 4; ++i) {
        const int r = row0 + ty * 4 + i;
        float4 v;
        v.x = acc[i][0] + bv.x; v.y = acc[i][1] + bv.y;
        v.z = acc[i][2] + bv.z; v.w = acc[i][3] + bv.w;
        if (RELU) {
            v.x = fmaxf(v.x, 0.f); v.y = fmaxf(v.y, 0.f);
            v.z = fmaxf(v.z, 0.f); v.w = fmaxf(v.w, 0.f);
        }
        *reinterpret_cast<float4*>(&C[(size_t)r * N + c0]) = v;
    }
}

// ---------------------------------------------------------------------------
// Per-row fused: hist segment-mean embedding + feature embeddings +
// 9x9 interaction upper-tri + final 100->128 projection.
// One block (128 threads) per batch row.
// ---------------------------------------------------------------------------
__global__ __launch_bounds__(128)
void embed_interact_proj(
    const int* __restrict__ hist_idx, const int* __restrict__ hist_off,
    const int* __restrict__ feat_idx,
    const float* __restrict__ Wq_c, const float* __restrict__ Wr_c,
    const float* __restrict__ Wq_f, const float* __restrict__ Wr_f,
    const float* __restrict__ dense, const float* __restrict__ Wp,
    const float* __restrict__ bp, float* __restrict__ out,
    int B, int Mtot)
{
    const int b = blockIdx.x;
    const int t = threadIdx.x;   // 128 threads

    __shared__ float T[NROWS][EMB_D + 1];   // +1 pad: pair-dot reads conflict-free
    __shared__ float comb[COMB];
    __shared__ int   sidx[128];

    // dense row -> T[0]
    if (t < EMB_D) T[0][t] = dense[(size_t)b * EMB_D + t];

    // feature embeddings -> T[2..8]
    for (int p = t; p < NFEAT * EMB_D; p += 128) {
        const int f = p >> 6, d = p & 63;
        const int fi = feat_idx[b * NFEAT + f];
        const int q = fi / C_FEAT, r = fi % C_FEAT;
        T[2 + f][d] = Wq_f[((size_t)f * NQ_FEAT + q) * EMB_D + d] *
                      Wr_f[((size_t)f * C_FEAT  + r) * EMB_D + d];
    }

    // hist segment mean -> T[1]
    const int start = hist_off[b];
    const int end   = (b + 1 < B) ? hist_off[b + 1] : Mtot;
    float acc = 0.f;
    for (int i0 = start; i0 < end; i0 += 128) {
        const int n = min(128, end - i0);
        __syncthreads();
        if (t < n) sidx[t] = hist_idx[i0 + t];
        __syncthreads();
        if (t < EMB_D) {
            for (int i = 0; i < n; ++i) {
                const int hi = sidx[i];
                const int q = hi / C_CAMP, r = hi % C_CAMP;
                acc += Wq_c[(size_t)q * EMB_D + t] * Wr_c[(size_t)r * EMB_D + t];
            }
        }
    }
    if (t < EMB_D) T[1][t] = acc / (float)(end - start);
    __syncthreads();

    // combined = [dense(64), triu(Z)(36)]
    if (t < EMB_D) comb[t] = T[0][t];
    if (t < NPAIRS) {
        int i = 0, rem = t;
        while (rem >= (NROWS - 1) - i) { rem -= (NROWS - 1) - i; ++i; }
        const int j = i + 1 + rem;
        float s = 0.f;
        #pragma unroll 8
        for (int d = 0; d < EMB_D; ++d) s += T[i][d] * T[j][d];
        comb[EMB_D + t] = s;
    }
    __syncthreads();

    // out[b] = comb @ Wp^T + bp   (Wp: [128][100])
    float a = bp[t];
    #pragma unroll 4
    for (int c = 0; c < COMB; ++c) a += comb[c] * Wp[t * COMB + c];
    out[(size_t)b * PROJ + t] = a;
}

// ---------------------------------------------------------------------------
extern "C" void kernel_launch(void* const* d_in, const int* in_sizes, int n_in,
                              void* d_out, int out_size, void* d_ws, size_t ws_size,
                              hipStream_t stream)
{
    const float* x        = (const float*)d_in[0];
    const int*   hist_idx = (const int*)  d_in[1];
    const int*   hist_off = (const int*)  d_in[2];
    const int*   feat_idx = (const int*)  d_in[3];
    const float* Wq_c     = (const float*)d_in[4];
    const float* Wr_c     = (const float*)d_in[5];
    const float* Wq_f     = (const float*)d_in[6];
    const float* Wr_f     = (const float*)d_in[7];
    const float* W0       = (const float*)d_in[8];
    const float* b0       = (const float*)d_in[9];
    const float* W1       = (const float*)d_in[10];
    const float* b1       = (const float*)d_in[11];
    const float* W2       = (const float*)d_in[12];
    const float* b2       = (const float*)d_in[13];
    const float* Wp       = (const float*)d_in[14];
    const float* bp       = (const float*)d_in[15];
    float* out = (float*)d_out;

    const int M    = in_sizes[0] / DENSE_D;   // 16384
    const int Mtot = in_sizes[1];             // B*HIST

    // workspace: h0 (M*512) | h1 (M*256) | dense (M*64)  ~ 54.5 MB
    float* h0 = (float*)d_ws;
    float* h1 = h0 + (size_t)M * HIDDEN1;
    float* dn = h1 + (size_t)M * HIDDEN2;

    gemm_bias_act<true ><<<dim3(M / 64, HIDDEN1 / 64), 256, 0, stream>>>(
        x,  W0, b0, h0, M, HIDDEN1, DENSE_D);
    gemm_bias_act<true ><<<dim3(M / 64, HIDDEN2 / 64), 256, 0, stream>>>(
        h0, W1, b1, h1, M, HIDDEN2, HIDDEN1);
    gemm_bias_act<false><<<dim3(M / 64, EMB_D   / 64), 256, 0, stream>>>(
        h1, W2, b2, dn, M, EMB_D,   HIDDEN2);

    embed_interact_proj<<<M, 128, 0, stream>>>(
        hist_idx, hist_off, feat_idx, Wq_c, Wr_c, Wq_f, Wr_f,
        dn, Wp, bp, out, M, Mtot);
}

// Round 2
// 116.946 us; speedup vs baseline: 2.6534x; 2.6534x over previous
//
#include <hip/hip_runtime.h>
#include <hip/hip_bf16.h>
#include <stdint.h>

#define DENSE_D 512
#define HIDDEN1 512
#define HIDDEN2 256
#define EMB_D   64
#define NFEAT   7
#define NROWS   9
#define NPAIRS  36
#define COMB    100          // 64 + 36
#define KPROJ   128          // padded K for projection GEMM
#define PROJ    128
#define C_CAMP  1000
#define C_FEAT  316
#define NQ_FEAT 317

typedef __attribute__((ext_vector_type(8))) __bf16 bf16x8;
typedef __attribute__((ext_vector_type(4))) float  facc4;

#define GLD_LDS16(gp, lp) __builtin_amdgcn_global_load_lds( \
    (__attribute__((address_space(1))) void*)(gp), \
    (__attribute__((address_space(3))) void*)(lp), 16, 0, 0)

// ---------------------------------------------------------------------------
// bf16 MFMA GEMM: C[M][N] = act(A[M][K] @ W[N][K]^T + bias)
// 256 threads = 4 waves (2x2), per-wave (BM/2)x(BN/2), 16x16x32 MFMA.
// LDS k-chunk-major [BK/8][R][8] so frag ds_read_b128 spreads bank-quads.
// ---------------------------------------------------------------------------
template<int BM, int BN, bool RELU, bool OUT_BF16>
__global__ __launch_bounds__(256)
void gemm_bf16(const __hip_bfloat16* __restrict__ A,
               const __hip_bfloat16* __restrict__ W,
               const float* __restrict__ bias,
               void* __restrict__ Cout,
               int M, int N, int K)
{
    constexpr int BK   = 32;
    constexpr int MREP = BM / 32;   // per-wave m-frags (2x2 wave grid)
    constexpr int NREP = BN / 32;
    constexpr int ACH  = BM * BK / 8;   // 16B chunks in A tile
    constexpr int BCH  = BN * BK / 8;

    __shared__ __align__(16) __hip_bfloat16 Asm[BK / 8][BM][8];
    __shared__ __align__(16) __hip_bfloat16 Bsm[BK / 8][BN][8];

    const int tid  = threadIdx.x;
    const int lane = tid & 63;
    const int wave = tid >> 6;
    const int wm   = wave >> 1;
    const int wn   = wave & 1;
    const int row0 = blockIdx.x * BM;
    const int col0 = blockIdx.y * BN;
    const int fr   = lane & 15;   // frag row/col
    const int fk   = lane >> 4;   // frag k-chunk

    facc4 acc[MREP][NREP] = {};

    for (int k0 = 0; k0 < K; k0 += BK) {
        #pragma unroll
        for (int it = 0; it < ACH / 256; ++it) {
            const int p  = it * 256 + tid;
            const int r  = p & (BM - 1);
            const int kc = p / BM;
            GLD_LDS16(A + (size_t)(row0 + r) * K + k0 + kc * 8,
                      (&Asm[0][0][0]) + (size_t)p * 8);
        }
        #pragma unroll
        for (int it = 0; it < BCH / 256; ++it) {
            const int p  = it * 256 + tid;
            const int r  = p & (BN - 1);
            const int kc = p / BN;
            GLD_LDS16(W + (size_t)(col0 + r) * K + k0 + kc * 8,
                      (&Bsm[0][0][0]) + (size_t)p * 8);
        }
        __syncthreads();   // compiler drains vmcnt before barrier

        bf16x8 af[MREP], bw[NREP];
        #pragma unroll
        for (int m = 0; m < MREP; ++m)
            af[m] = *reinterpret_cast<const bf16x8*>(
                &Asm[fk][wm * (MREP * 16) + m * 16 + fr][0]);
        #pragma unroll
        for (int n = 0; n < NREP; ++n)
            bw[n] = *reinterpret_cast<const bf16x8*>(
                &Bsm[fk][wn * (NREP * 16) + n * 16 + fr][0]);
        #pragma unroll
        for (int m = 0; m < MREP; ++m)
            #pragma unroll
            for (int n = 0; n < NREP; ++n)
                acc[m][n] = __builtin_amdgcn_mfma_f32_16x16x32_bf16(
                    af[m], bw[n], acc[m][n], 0, 0, 0);
        __syncthreads();
    }

    // epilogue: C/D layout col=lane&15, row=(lane>>4)*4+j  [m89/m91-verified]
    #pragma unroll
    for (int n = 0; n < NREP; ++n) {
        const int col = col0 + wn * (NREP * 16) + n * 16 + fr;
        const float bv = bias[col];
        #pragma unroll
        for (int m = 0; m < MREP; ++m) {
            #pragma unroll
            for (int j = 0; j < 4; ++j) {
                const int row = row0 + wm * (MREP * 16) + m * 16 + fk * 4 + j;
                float v = acc[m][n][j] + bv;
                if (RELU) v = fmaxf(v, 0.f);
                if (OUT_BF16)
                    ((__hip_bfloat16*)Cout)[(size_t)row * N + col] = __float2bfloat16(v);
                else
                    ((float*)Cout)[(size_t)row * N + col] = v;
            }
        }
    }
}

// ---------------------------------------------------------------------------
// fp32 -> bf16 cast, 4 elems/thread
// ---------------------------------------------------------------------------
__global__ void cast_f32_bf16_v4(const float* __restrict__ in,
                                 __hip_bfloat16* __restrict__ out, int n4)
{
    int i = blockIdx.x * blockDim.x + threadIdx.x;
    const int stride = gridDim.x * blockDim.x;
    for (; i < n4; i += stride) {
        const float4 v = reinterpret_cast<const float4*>(in)[i];
        union { __hip_bfloat16 h[4]; ushort4 u; } cv;
        cv.h[0] = __float2bfloat16(v.x);
        cv.h[1] = __float2bfloat16(v.y);
        cv.h[2] = __float2bfloat16(v.z);
        cv.h[3] = __float2bfloat16(v.w);
        reinterpret_cast<ushort4*>(out)[i] = cv.u;
    }
}

// Wp [128][100] fp32 -> [128][128] bf16 zero-padded
__global__ void pad_wp_bf16(const float* __restrict__ Wp,
                            __hip_bfloat16* __restrict__ out)
{
    const int t = blockIdx.x * blockDim.x + threadIdx.x;  // 16384 threads
    const int r = t >> 7, c = t & 127;
    out[t] = __float2bfloat16(c < COMB ? Wp[r * COMB + c] : 0.f);
}

// ---------------------------------------------------------------------------
// Per-row fused: hist segment-mean + feature embeddings + 9x9 upper-tri
// interaction -> combined row [dense(64) | Z(36) | 0-pad(28)] as bf16.
// ---------------------------------------------------------------------------
__global__ __launch_bounds__(128)
void embed_interact(
    const int* __restrict__ hist_idx, const int* __restrict__ hist_off,
    const int* __restrict__ feat_idx,
    const float* __restrict__ Wq_c, const float* __restrict__ Wr_c,
    const float* __restrict__ Wq_f, const float* __restrict__ Wr_f,
    const float* __restrict__ dense, __hip_bfloat16* __restrict__ comb,
    int B, int Mtot)
{
    const int b = blockIdx.x;
    const int t = threadIdx.x;
    const int d = t & 63, half = t >> 6;

    __shared__ float T[NROWS][EMB_D + 1];
    __shared__ float part[EMB_D];
    __shared__ float zf[NPAIRS];
    __shared__ int   sidx[128];

    if (t < EMB_D) T[0][t] = dense[(size_t)b * EMB_D + t];

    for (int p = t; p < NFEAT * EMB_D; p += 128) {
        const int f = p >> 6, dd = p & 63;
        const int fi = feat_idx[b * NFEAT + f];
        const int q = fi / C_FEAT, r = fi % C_FEAT;
        T[2 + f][dd] = Wq_f[((size_t)f * NQ_FEAT + q) * EMB_D + dd] *
                       Wr_f[((size_t)f * C_FEAT  + r) * EMB_D + dd];
    }

    const int start = hist_off[b];
    const int end   = (b + 1 < B) ? hist_off[b + 1] : Mtot;
    float acc = 0.f;
    for (int i0 = start; i0 < end; i0 += 128) {
        const int n = min(128, end - i0);
        __syncthreads();
        if (t < n) sidx[t] = hist_idx[i0 + t];
        __syncthreads();
        for (int i = half; i < n; i += 2) {
            const int hi = sidx[i];
            const int q = hi / C_CAMP, r = hi % C_CAMP;
            acc += Wq_c[(size_t)q * EMB_D + d] * Wr_c[(size_t)r * EMB_D + d];
        }
    }
    if (half == 1) part[d] = acc;
    __syncthreads();
    if (t < EMB_D) {
        const int cnt = end - start;
        T[1][t] = (acc + part[t]) / (float)max(cnt, 1);
    }
    __syncthreads();

    if (t < NPAIRS) {
        int i = 0, rem = t;
        while (rem >= (NROWS - 1) - i) { rem -= (NROWS - 1) - i; ++i; }
        const int j = i + 1 + rem;
        float s = 0.f;
        #pragma unroll 8
        for (int dd = 0; dd < EMB_D; ++dd) s += T[i][dd] * T[j][dd];
        zf[t] = s;
    }
    __syncthreads();

    float v;
    if (t < EMB_D)      v = T[0][t];
    else if (t < COMB)  v = zf[t - EMB_D];
    else                v = 0.f;
    comb[(size_t)b * KPROJ + t] = __float2bfloat16(v);
}

// ---------------------------------------------------------------------------
extern "C" void kernel_launch(void* const* d_in, const int* in_sizes, int n_in,
                              void* d_out, int out_size, void* d_ws, size_t ws_size,
                              hipStream_t stream)
{
    const float* x        = (const float*)d_in[0];
    const int*   hist_idx = (const int*)  d_in[1];
    const int*   hist_off = (const int*)  d_in[2];
    const int*   feat_idx = (const int*)  d_in[3];
    const float* Wq_c     = (const float*)d_in[4];
    const float* Wr_c     = (const float*)d_in[5];
    const float* Wq_f     = (const float*)d_in[6];
    const float* Wr_f     = (const float*)d_in[7];
    const float* W0       = (const float*)d_in[8];
    const float* b0       = (const float*)d_in[9];
    const float* W1       = (const float*)d_in[10];
    const float* b1       = (const float*)d_in[11];
    const float* W2       = (const float*)d_in[12];
    const float* b2       = (const float*)d_in[13];
    const float* Wp       = (const float*)d_in[14];
    const float* bp       = (const float*)d_in[15];

    const int M    = in_sizes[0] / DENSE_D;   // 16384
    const int Mtot = in_sizes[1];             // B*HIST

    char* w = (char*)d_ws;
    __hip_bfloat16* xb  = (__hip_bfloat16*)w; w += (size_t)M * DENSE_D * 2;
    __hip_bfloat16* w0b = (__hip_bfloat16*)w; w += HIDDEN1 * DENSE_D * 2;
    __hip_bfloat16* w1b = (__hip_bfloat16*)w; w += HIDDEN2 * HIDDEN1 * 2;
    __hip_bfloat16* w2b = (__hip_bfloat16*)w; w += EMB_D * HIDDEN2 * 2;
    __hip_bfloat16* wpb = (__hip_bfloat16*)w; w += PROJ * KPROJ * 2;
    __hip_bfloat16* h0b = (__hip_bfloat16*)w; w += (size_t)M * HIDDEN1 * 2;
    __hip_bfloat16* h1b = (__hip_bfloat16*)w; w += (size_t)M * HIDDEN2 * 2;
    float*          dn  = (float*)w;          w += (size_t)M * EMB_D * 4;
    __hip_bfloat16* cmb = (__hip_bfloat16*)w; w += (size_t)M * KPROJ * 2;

    cast_f32_bf16_v4<<<2048, 256, 0, stream>>>(x,  xb,  M * DENSE_D / 4);
    cast_f32_bf16_v4<<<256,  256, 0, stream>>>(W0, w0b, HIDDEN1 * DENSE_D / 4);
    cast_f32_bf16_v4<<<128,  256, 0, stream>>>(W1, w1b, HIDDEN2 * HIDDEN1 / 4);
    cast_f32_bf16_v4<<<16,   256, 0, stream>>>(W2, w2b, EMB_D * HIDDEN2 / 4);
    pad_wp_bf16<<<64, 256, 0, stream>>>(Wp, wpb);

    gemm_bf16<128, 128, true,  true ><<<dim3(M / 128, HIDDEN1 / 128), 256, 0, stream>>>(
        xb,  w0b, b0, h0b, M, HIDDEN1, DENSE_D);
    gemm_bf16<128, 64,  true,  true ><<<dim3(M / 128, HIDDEN2 / 64), 256, 0, stream>>>(
        h0b, w1b, b1, h1b, M, HIDDEN2, HIDDEN1);
    gemm_bf16<64,  64,  false, false><<<dim3(M / 64, EMB_D / 64), 256, 0, stream>>>(
        h1b, w2b, b2, dn, M, EMB_D, HIDDEN2);

    embed_interact<<<M, 128, 0, stream>>>(
        hist_idx, hist_off, feat_idx, Wq_c, Wr_c, Wq_f, Wr_f,
        dn, cmb, M, Mtot);

    gemm_bf16<64, 64, false, false><<<dim3(M / 64, PROJ / 64), 256, 0, stream>>>(
        cmb, wpb, bp, (float*)d_out, M, PROJ, KPROJ);
}

// Round 3
// 99.518 us; speedup vs baseline: 3.1181x; 1.1751x over previous
//
#include <hip/hip_runtime.h>
#include <hip/hip_bf16.h>
#include <stdint.h>

#define DENSE_D 512
#define HIDDEN1 512
#define HIDDEN2 256
#define EMB_D   64
#define NFEAT   7
#define NROWS   9
#define NPAIRS  36
#define COMB    100          // 64 + 36
#define KPROJ   128          // padded K for projection GEMM
#define PROJ    128
#define C_CAMP  1000
#define C_FEAT  316
#define NQ_FEAT 317

typedef __attribute__((ext_vector_type(8))) __bf16 bf16x8;
typedef __attribute__((ext_vector_type(8))) unsigned short ushort8;
typedef __attribute__((ext_vector_type(4))) float  facc4;

#define GLD_LDS16(gp, lp) __builtin_amdgcn_global_load_lds( \
    (__attribute__((address_space(1))) void*)(gp), \
    (__attribute__((address_space(3))) void*)(lp), 16, 0, 0)

__device__ inline unsigned short f2bf(float f) {
    __hip_bfloat16 h = __float2bfloat16(f);
    return *reinterpret_cast<unsigned short*>(&h);
}
__device__ inline float blo(unsigned int u) { return __uint_as_float(u << 16); }
__device__ inline float bhi(unsigned int u) { return __uint_as_float(u & 0xffff0000u); }

// ---------------------------------------------------------------------------
// bf16 MFMA GEMM: C[M][N] = act(A[M][K] @ W[N][K]^T + bias)
// 256 threads = 4 waves (2x2), 16x16x32 MFMA, LDS k-chunk-major [BK/8][R][8].
// A_F32: A is fp32, cast to bf16 during reg-staging (W stays global_load_lds).
// ---------------------------------------------------------------------------
template<int BM, int BN, bool RELU, bool OUT_BF16, bool A_F32>
__global__ __launch_bounds__(256)
void gemm_bf16(const void* __restrict__ Avoid,
               const __hip_bfloat16* __restrict__ W,
               const float* __restrict__ bias,
               void* __restrict__ Cout,
               int M, int N, int K)
{
    constexpr int BK   = 32;
    constexpr int MREP = BM / 32;
    constexpr int NREP = BN / 32;
    constexpr int ACH  = BM * BK / 8;
    constexpr int BCH  = BN * BK / 8;

    __shared__ __align__(16) __hip_bfloat16 Asm[BK / 8][BM][8];
    __shared__ __align__(16) __hip_bfloat16 Bsm[BK / 8][BN][8];

    const int tid  = threadIdx.x;
    const int lane = tid & 63;
    const int wave = tid >> 6;
    const int wm   = wave >> 1;
    const int wn   = wave & 1;
    const int row0 = blockIdx.x * BM;
    const int col0 = blockIdx.y * BN;
    const int fr   = lane & 15;
    const int fk   = lane >> 4;

    facc4 acc[MREP][NREP] = {};

    for (int k0 = 0; k0 < K; k0 += BK) {
        if (A_F32) {
            const float* Af = (const float*)Avoid;
            #pragma unroll
            for (int it = 0; it < ACH / 256; ++it) {
                const int p  = it * 256 + tid;
                const int r  = p & (BM - 1);
                const int kc = p / BM;
                const float* src = Af + (size_t)(row0 + r) * K + k0 + kc * 8;
                const float4 v0 = *reinterpret_cast<const float4*>(src);
                const float4 v1 = *reinterpret_cast<const float4*>(src + 4);
                ushort8 cv;
                cv[0] = f2bf(v0.x); cv[1] = f2bf(v0.y);
                cv[2] = f2bf(v0.z); cv[3] = f2bf(v0.w);
                cv[4] = f2bf(v1.x); cv[5] = f2bf(v1.y);
                cv[6] = f2bf(v1.z); cv[7] = f2bf(v1.w);
                *reinterpret_cast<ushort8*>((&Asm[0][0][0]) + (size_t)p * 8) = cv;
            }
        } else {
            const __hip_bfloat16* Ab = (const __hip_bfloat16*)Avoid;
            #pragma unroll
            for (int it = 0; it < ACH / 256; ++it) {
                const int p  = it * 256 + tid;
                const int r  = p & (BM - 1);
                const int kc = p / BM;
                GLD_LDS16(Ab + (size_t)(row0 + r) * K + k0 + kc * 8,
                          (&Asm[0][0][0]) + (size_t)p * 8);
            }
        }
        #pragma unroll
        for (int it = 0; it < BCH / 256; ++it) {
            const int p  = it * 256 + tid;
            const int r  = p & (BN - 1);
            const int kc = p / BN;
            GLD_LDS16(W + (size_t)(col0 + r) * K + k0 + kc * 8,
                      (&Bsm[0][0][0]) + (size_t)p * 8);
        }
        __syncthreads();

        bf16x8 af[MREP], bw[NREP];
        #pragma unroll
        for (int m = 0; m < MREP; ++m)
            af[m] = *reinterpret_cast<const bf16x8*>(
                &Asm[fk][wm * (MREP * 16) + m * 16 + fr][0]);
        #pragma unroll
        for (int n = 0; n < NREP; ++n)
            bw[n] = *reinterpret_cast<const bf16x8*>(
                &Bsm[fk][wn * (NREP * 16) + n * 16 + fr][0]);
        #pragma unroll
        for (int m = 0; m < MREP; ++m)
            #pragma unroll
            for (int n = 0; n < NREP; ++n)
                acc[m][n] = __builtin_amdgcn_mfma_f32_16x16x32_bf16(
                    af[m], bw[n], acc[m][n], 0, 0, 0);
        __syncthreads();
    }

    #pragma unroll
    for (int n = 0; n < NREP; ++n) {
        const int col = col0 + wn * (NREP * 16) + n * 16 + fr;
        const float bv = bias[col];
        #pragma unroll
        for (int m = 0; m < MREP; ++m) {
            #pragma unroll
            for (int j = 0; j < 4; ++j) {
                const int row = row0 + wm * (MREP * 16) + m * 16 + fk * 4 + j;
                float v = acc[m][n][j] + bv;
                if (RELU) v = fmaxf(v, 0.f);
                if (OUT_BF16)
                    ((__hip_bfloat16*)Cout)[(size_t)row * N + col] = __float2bfloat16(v);
                else
                    ((float*)Cout)[(size_t)row * N + col] = v;
            }
        }
    }
}

// ---------------------------------------------------------------------------
// One-shot prep: cast all weights/tables to bf16, pad Wp to [128][128].
// ---------------------------------------------------------------------------
__device__ inline void cast_seg(const float* __restrict__ src,
                                unsigned short* __restrict__ dst,
                                int n4, int id, int stride)
{
    for (int i = id; i < n4; i += stride) {
        const float4 v = reinterpret_cast<const float4*>(src)[i];
        ushort4 o;
        o.x = f2bf(v.x); o.y = f2bf(v.y); o.z = f2bf(v.z); o.w = f2bf(v.w);
        reinterpret_cast<ushort4*>(dst)[i] = o;
    }
}

__global__ __launch_bounds__(256)
void prep_all(const float* __restrict__ W0, const float* __restrict__ W1,
              const float* __restrict__ W2, const float* __restrict__ Wp,
              const float* __restrict__ Wq_c, const float* __restrict__ Wr_c,
              const float* __restrict__ Wq_f, const float* __restrict__ Wr_f,
              unsigned short* w0b, unsigned short* w1b, unsigned short* w2b,
              unsigned short* wpb, unsigned short* qcb, unsigned short* rcb,
              unsigned short* qfb, unsigned short* rfb)
{
    const int id = blockIdx.x * blockDim.x + threadIdx.x;
    const int stride = gridDim.x * blockDim.x;
    cast_seg(W0,   w0b, HIDDEN1 * DENSE_D / 4, id, stride);
    cast_seg(W1,   w1b, HIDDEN2 * HIDDEN1 / 4, id, stride);
    cast_seg(W2,   w2b, EMB_D * HIDDEN2 / 4,   id, stride);
    cast_seg(Wq_c, qcb, C_CAMP * EMB_D / 4,    id, stride);
    cast_seg(Wr_c, rcb, C_CAMP * EMB_D / 4,    id, stride);
    cast_seg(Wq_f, qfb, NFEAT * NQ_FEAT * EMB_D / 4, id, stride);
    cast_seg(Wr_f, rfb, NFEAT * C_FEAT * EMB_D / 4,  id, stride);
    for (int i = id; i < PROJ * KPROJ; i += stride) {
        const int r = i >> 7, c = i & 127;
        wpb[i] = (c < COMB) ? f2bf(Wp[r * COMB + c]) : (unsigned short)0;
    }
}

// ---------------------------------------------------------------------------
// Per-row fused: hist segment-mean (bf16 tables, uint2 gathers, hoisted
// div/mod, 16-way item parallel) + feature embeddings + 9x9 interaction ->
// combined row [dense(64) | Z(36) | pad(28)] bf16.
// ---------------------------------------------------------------------------
__global__ __launch_bounds__(256)
void embed_interact(
    const int* __restrict__ hist_idx, const int* __restrict__ hist_off,
    const int* __restrict__ feat_idx,
    const unsigned short* __restrict__ Wq_cb, const unsigned short* __restrict__ Wr_cb,
    const unsigned short* __restrict__ Wq_fb, const unsigned short* __restrict__ Wr_fb,
    const unsigned short* __restrict__ dense,
    unsigned short* __restrict__ comb, int B, int Mtot)
{
    const int b = blockIdx.x;
    const int t = threadIdx.x;   // 256

    __shared__ float T[NROWS][EMB_D + 1];
    __shared__ float part[16][68];
    __shared__ int2  soff[128];
    __shared__ float zf[NPAIRS];

    // dense row -> T[0]  (threads 0..15, 4 dims each)
    if (t < 16) {
        const uint2 u = reinterpret_cast<const uint2*>(dense + (size_t)b * EMB_D)[t];
        T[0][t * 4 + 0] = blo(u.x); T[0][t * 4 + 1] = bhi(u.x);
        T[0][t * 4 + 2] = blo(u.y); T[0][t * 4 + 3] = bhi(u.y);
    }
    // feature embeddings -> T[2..8]  (threads 64..175, 16 per feature)
    if (t >= 64 && t < 64 + NFEAT * 16) {
        const int p = t - 64;
        const int f = p >> 4, fd2 = p & 15;
        const int fi = feat_idx[b * NFEAT + f];
        const int q = fi / C_FEAT, r = fi - q * C_FEAT;
        const uint2 qv = *reinterpret_cast<const uint2*>(
            Wq_fb + ((size_t)f * NQ_FEAT + q) * EMB_D + fd2 * 4);
        const uint2 rv = *reinterpret_cast<const uint2*>(
            Wr_fb + ((size_t)f * C_FEAT + r) * EMB_D + fd2 * 4);
        T[2 + f][fd2 * 4 + 0] = blo(qv.x) * blo(rv.x);
        T[2 + f][fd2 * 4 + 1] = bhi(qv.x) * bhi(rv.x);
        T[2 + f][fd2 * 4 + 2] = blo(qv.y) * blo(rv.y);
        T[2 + f][fd2 * 4 + 3] = bhi(qv.y) * bhi(rv.y);
    }

    // hist segment mean -> T[1]
    const int start = hist_off[b];
    const int end   = (b + 1 < B) ? hist_off[b + 1] : Mtot;
    const int cnt   = end - start;
    const int d2 = t & 15;   // d-quad
    const int g  = t >> 4;   // item group 0..15
    float a0 = 0.f, a1 = 0.f, a2 = 0.f, a3 = 0.f;
    for (int i0 = start; i0 < end; i0 += 128) {
        const int n = min(128, end - i0);
        __syncthreads();
        if (t < n) {
            const int hi = hist_idx[i0 + t];
            const int q = hi / C_CAMP;
            const int r = hi - q * C_CAMP;
            soff[t] = make_int2(q * EMB_D, r * EMB_D);
        }
        __syncthreads();
        for (int i = g; i < n; i += 16) {
            const int2 o = soff[i];
            const uint2 qv = *reinterpret_cast<const uint2*>(Wq_cb + o.x + d2 * 4);
            const uint2 rv = *reinterpret_cast<const uint2*>(Wr_cb + o.y + d2 * 4);
            a0 += blo(qv.x) * blo(rv.x);
            a1 += bhi(qv.x) * bhi(rv.x);
            a2 += blo(qv.y) * blo(rv.y);
            a3 += bhi(qv.y) * bhi(rv.y);
        }
    }
    part[g][d2 * 4 + 0] = a0; part[g][d2 * 4 + 1] = a1;
    part[g][d2 * 4 + 2] = a2; part[g][d2 * 4 + 3] = a3;
    __syncthreads();
    if (t < EMB_D) {
        float s = 0.f;
        #pragma unroll
        for (int gg = 0; gg < 16; ++gg) s += part[gg][t];
        T[1][t] = s / (float)max(cnt, 1);
    }
    __syncthreads();

    // Z upper-tri: 4 threads per pair, 16 dims each, shuffle-reduce
    if (t < NPAIRS * 4) {
        const int p = t >> 2, sub = t & 3;
        int ii = 0, rem = p;
        while (rem >= (NROWS - 1) - ii) { rem -= (NROWS - 1) - ii; ++ii; }
        const int jj = ii + 1 + rem;
        float s = 0.f;
        const int dbase = sub * 16;
        #pragma unroll
        for (int dd = 0; dd < 16; ++dd) s += T[ii][dbase + dd] * T[jj][dbase + dd];
        s += __shfl_xor(s, 1);
        s += __shfl_xor(s, 2);
        if (sub == 0) zf[p] = s;
    }
    __syncthreads();

    if (t < KPROJ) {
        const float v = (t < EMB_D) ? T[0][t] : (t < COMB ? zf[t - EMB_D] : 0.f);
        comb[(size_t)b * KPROJ + t] = f2bf(v);
    }
}

// ---------------------------------------------------------------------------
extern "C" void kernel_launch(void* const* d_in, const int* in_sizes, int n_in,
                              void* d_out, int out_size, void* d_ws, size_t ws_size,
                              hipStream_t stream)
{
    const float* x        = (const float*)d_in[0];
    const int*   hist_idx = (const int*)  d_in[1];
    const int*   hist_off = (const int*)  d_in[2];
    const int*   feat_idx = (const int*)  d_in[3];
    const float* Wq_c     = (const float*)d_in[4];
    const float* Wr_c     = (const float*)d_in[5];
    const float* Wq_f     = (const float*)d_in[6];
    const float* Wr_f     = (const float*)d_in[7];
    const float* W0       = (const float*)d_in[8];
    const float* b0       = (const float*)d_in[9];
    const float* W1       = (const float*)d_in[10];
    const float* b1       = (const float*)d_in[11];
    const float* W2       = (const float*)d_in[12];
    const float* b2       = (const float*)d_in[13];
    const float* Wp       = (const float*)d_in[14];
    const float* bp       = (const float*)d_in[15];

    const int M    = in_sizes[0] / DENSE_D;   // 16384
    const int Mtot = in_sizes[1];             // B*HIST

    char* w = (char*)d_ws;
    auto take = [&](size_t bytes) { char* p = w; w += (bytes + 255) & ~(size_t)255; return p; };
    unsigned short* w0b = (unsigned short*)take(HIDDEN1 * DENSE_D * 2);
    unsigned short* w1b = (unsigned short*)take(HIDDEN2 * HIDDEN1 * 2);
    unsigned short* w2b = (unsigned short*)take(EMB_D * HIDDEN2 * 2);
    unsigned short* wpb = (unsigned short*)take(PROJ * KPROJ * 2);
    unsigned short* qcb = (unsigned short*)take(C_CAMP * EMB_D * 2);
    unsigned short* rcb = (unsigned short*)take(C_CAMP * EMB_D * 2);
    unsigned short* qfb = (unsigned short*)take(NFEAT * NQ_FEAT * EMB_D * 2);
    unsigned short* rfb = (unsigned short*)take(NFEAT * C_FEAT * EMB_D * 2);
    unsigned short* h0b = (unsigned short*)take((size_t)M * HIDDEN1 * 2);
    unsigned short* h1b = (unsigned short*)take((size_t)M * HIDDEN2 * 2);
    unsigned short* dnb = (unsigned short*)take((size_t)M * EMB_D * 2);
    unsigned short* cmb = (unsigned short*)take((size_t)M * KPROJ * 2);

    prep_all<<<512, 256, 0, stream>>>(W0, W1, W2, Wp, Wq_c, Wr_c, Wq_f, Wr_f,
                                      w0b, w1b, w2b, wpb, qcb, rcb, qfb, rfb);

    gemm_bf16<128, 128, true, true, true><<<dim3(M / 128, HIDDEN1 / 128), 256, 0, stream>>>(
        x, (const __hip_bfloat16*)w0b, b0, h0b, M, HIDDEN1, DENSE_D);
    gemm_bf16<128, 64, true, true, false><<<dim3(M / 128, HIDDEN2 / 64), 256, 0, stream>>>(
        h0b, (const __hip_bfloat16*)w1b, b1, h1b, M, HIDDEN2, HIDDEN1);
    gemm_bf16<64, 64, false, true, false><<<dim3(M / 64, EMB_D / 64), 256, 0, stream>>>(
        h1b, (const __hip_bfloat16*)w2b, b2, dnb, M, EMB_D, HIDDEN2);

    embed_interact<<<M, 256, 0, stream>>>(
        hist_idx, hist_off, feat_idx, qcb, rcb, qfb, rfb, dnb, cmb, M, Mtot);

    gemm_bf16<64, 64, false, false, false><<<dim3(M / 64, PROJ / 64), 256, 0, stream>>>(
        cmb, (const __hip_bfloat16*)wpb, bp, (float*)d_out, M, PROJ, KPROJ);
}

// Round 4
// 87.668 us; speedup vs baseline: 3.5395x; 1.1352x over previous
//
#include <hip/hip_runtime.h>
#include <hip/hip_bf16.h>
#include <stdint.h>

#define DENSE_D 512
#define HIDDEN1 512
#define HIDDEN2 256
#define EMB_D   64
#define NFEAT   7
#define NROWS   9
#define NPAIRS  36
#define COMB    100          // 64 + 36
#define KPROJ   128          // padded K for projection GEMM
#define PROJ    128
#define C_CAMP  1000
#define C_FEAT  316
#define NQ_FEAT 317

typedef __attribute__((ext_vector_type(8))) __bf16 bf16x8;
typedef __attribute__((ext_vector_type(8))) unsigned short ushort8;
typedef __attribute__((ext_vector_type(4))) float  facc4;

#define GLD_LDS16(gp, lp) __builtin_amdgcn_global_load_lds( \
    (__attribute__((address_space(1))) void*)(gp), \
    (__attribute__((address_space(3))) void*)(lp), 16, 0, 0)

__device__ inline unsigned short f2bf(float f) {
    __hip_bfloat16 h = __float2bfloat16(f);
    return *reinterpret_cast<unsigned short*>(&h);
}
__device__ inline float blo(unsigned int u) { return __uint_as_float(u << 16); }
__device__ inline float bhi(unsigned int u) { return __uint_as_float(u & 0xffff0000u); }

// ---------------------------------------------------------------------------
// bf16 MFMA GEMM: C[M][N] = act(A[M][K] @ W[N][K]^T + bias)
// WM x WN waves, per-wave (BM/WM)x(BN/WN), 16x16x32 MFMA.
// LDS k-chunk-major [BK/8][R][8]. A_F32: A fp32, cast during reg-staging.
// ---------------------------------------------------------------------------
template<int BM, int BN, int WM, int WN, bool RELU, bool OUT_BF16, bool A_F32>
__global__ __launch_bounds__(WM * WN * 64)
void gemm_bf16(const void* __restrict__ Avoid,
               const __hip_bfloat16* __restrict__ W,
               const float* __restrict__ bias,
               void* __restrict__ Cout,
               int M, int N, int K)
{
    constexpr int BK      = 32;
    constexpr int THREADS = WM * WN * 64;
    constexpr int MREP    = BM / (WM * 16);
    constexpr int NREP    = BN / (WN * 16);
    constexpr int ACH     = BM * BK / 8;
    constexpr int BCH     = BN * BK / 8;

    __shared__ __align__(16) __hip_bfloat16 Asm[BK / 8][BM][8];
    __shared__ __align__(16) __hip_bfloat16 Bsm[BK / 8][BN][8];

    const int tid  = threadIdx.x;
    const int lane = tid & 63;
    const int wave = tid >> 6;
    const int wm   = wave / WN;
    const int wn   = wave % WN;
    const int row0 = blockIdx.x * BM;
    const int col0 = blockIdx.y * BN;
    const int fr   = lane & 15;
    const int fk   = lane >> 4;

    facc4 acc[MREP][NREP] = {};

    for (int k0 = 0; k0 < K; k0 += BK) {
        if (A_F32) {
            const float* Af = (const float*)Avoid;
            for (int p = tid; p < ACH; p += THREADS) {
                const int r  = p & (BM - 1);
                const int kc = p / BM;
                const float* src = Af + (size_t)(row0 + r) * K + k0 + kc * 8;
                const float4 v0 = *reinterpret_cast<const float4*>(src);
                const float4 v1 = *reinterpret_cast<const float4*>(src + 4);
                ushort8 cv;
                cv[0] = f2bf(v0.x); cv[1] = f2bf(v0.y);
                cv[2] = f2bf(v0.z); cv[3] = f2bf(v0.w);
                cv[4] = f2bf(v1.x); cv[5] = f2bf(v1.y);
                cv[6] = f2bf(v1.z); cv[7] = f2bf(v1.w);
                *reinterpret_cast<ushort8*>(
                    (unsigned short*)(&Asm[0][0][0]) + (size_t)p * 8) = cv;
            }
        } else {
            const __hip_bfloat16* Ab = (const __hip_bfloat16*)Avoid;
            for (int p = tid; p < ACH; p += THREADS) {
                const int r  = p & (BM - 1);
                const int kc = p / BM;
                GLD_LDS16(Ab + (size_t)(row0 + r) * K + k0 + kc * 8,
                          (&Asm[0][0][0]) + (size_t)p * 8);
            }
        }
        for (int p = tid; p < BCH; p += THREADS) {
            const int r  = p & (BN - 1);
            const int kc = p / BN;
            GLD_LDS16(W + (size_t)(col0 + r) * K + k0 + kc * 8,
                      (&Bsm[0][0][0]) + (size_t)p * 8);
        }
        __syncthreads();

        bf16x8 af[MREP], bw[NREP];
        #pragma unroll
        for (int m = 0; m < MREP; ++m)
            af[m] = *reinterpret_cast<const bf16x8*>(
                &Asm[fk][wm * (MREP * 16) + m * 16 + fr][0]);
        #pragma unroll
        for (int n = 0; n < NREP; ++n)
            bw[n] = *reinterpret_cast<const bf16x8*>(
                &Bsm[fk][wn * (NREP * 16) + n * 16 + fr][0]);
        #pragma unroll
        for (int m = 0; m < MREP; ++m)
            #pragma unroll
            for (int n = 0; n < NREP; ++n)
                acc[m][n] = __builtin_amdgcn_mfma_f32_16x16x32_bf16(
                    af[m], bw[n], acc[m][n], 0, 0, 0);
        __syncthreads();
    }

    #pragma unroll
    for (int n = 0; n < NREP; ++n) {
        const int col = col0 + wn * (NREP * 16) + n * 16 + fr;
        const float bv = bias[col];
        #pragma unroll
        for (int m = 0; m < MREP; ++m) {
            #pragma unroll
            for (int j = 0; j < 4; ++j) {
                const int row = row0 + wm * (MREP * 16) + m * 16 + fk * 4 + j;
                float v = acc[m][n][j] + bv;
                if (RELU) v = fmaxf(v, 0.f);
                if (OUT_BF16)
                    ((__hip_bfloat16*)Cout)[(size_t)row * N + col] = __float2bfloat16(v);
                else
                    ((float*)Cout)[(size_t)row * N + col] = v;
            }
        }
    }
}

// ---------------------------------------------------------------------------
// One-shot prep: cast all weights/tables to bf16, pad Wp to [128][128].
// ---------------------------------------------------------------------------
__device__ inline void cast_seg(const float* __restrict__ src,
                                unsigned short* __restrict__ dst,
                                int n4, int id, int stride)
{
    for (int i = id; i < n4; i += stride) {
        const float4 v = reinterpret_cast<const float4*>(src)[i];
        ushort4 o;
        o.x = f2bf(v.x); o.y = f2bf(v.y); o.z = f2bf(v.z); o.w = f2bf(v.w);
        reinterpret_cast<ushort4*>(dst)[i] = o;
    }
}

__global__ __launch_bounds__(256)
void prep_all(const float* __restrict__ W0, const float* __restrict__ W1,
              const float* __restrict__ W2, const float* __restrict__ Wp,
              const float* __restrict__ Wq_c, const float* __restrict__ Wr_c,
              const float* __restrict__ Wq_f, const float* __restrict__ Wr_f,
              unsigned short* w0b, unsigned short* w1b, unsigned short* w2b,
              unsigned short* wpb, unsigned short* qcb, unsigned short* rcb,
              unsigned short* qfb, unsigned short* rfb)
{
    const int id = blockIdx.x * blockDim.x + threadIdx.x;
    const int stride = gridDim.x * blockDim.x;
    cast_seg(W0,   w0b, HIDDEN1 * DENSE_D / 4, id, stride);
    cast_seg(W1,   w1b, HIDDEN2 * HIDDEN1 / 4, id, stride);
    cast_seg(W2,   w2b, EMB_D * HIDDEN2 / 4,   id, stride);
    cast_seg(Wq_c, qcb, C_CAMP * EMB_D / 4,    id, stride);
    cast_seg(Wr_c, rcb, C_CAMP * EMB_D / 4,    id, stride);
    cast_seg(Wq_f, qfb, NFEAT * NQ_FEAT * EMB_D / 4, id, stride);
    cast_seg(Wr_f, rfb, NFEAT * C_FEAT * EMB_D / 4,  id, stride);
    for (int i = id; i < PROJ * KPROJ; i += stride) {
        const int r = i >> 7, c = i & 127;
        wpb[i] = (c < COMB) ? f2bf(Wp[r * COMB + c]) : (unsigned short)0;
    }
}

// ---------------------------------------------------------------------------
// Fused tail: per block = 32 rows.
//  1) GEMM2: dense = h1[32x256] @ W2^T + b2   (A LDS-free: direct global frags)
//  2) hist segment-mean + feature embeddings -> T (bf16, padded stride 68)
//  3) 9x9 upper-tri interactions -> combs (padded stride 136)
//  4) proj: out = combs @ Wp^T + bp           (B direct global frags)
// ---------------------------------------------------------------------------
__global__ __launch_bounds__(256)
void tail_fused(const unsigned short* __restrict__ h1b,
                const unsigned short* __restrict__ w2b,
                const float* __restrict__ b2,
                const int* __restrict__ hist_idx,
                const int* __restrict__ hist_off,
                const int* __restrict__ feat_idx,
                const unsigned short* __restrict__ qcb,
                const unsigned short* __restrict__ rcb,
                const unsigned short* __restrict__ qfb,
                const unsigned short* __restrict__ rfb,
                const unsigned short* __restrict__ wpb,
                const float* __restrict__ bp,
                float* __restrict__ out,
                int B, int Mtot)
{
    const int r0   = blockIdx.x * 32;
    const int t    = threadIdx.x;       // 256
    const int lane = t & 63;
    const int wave = t >> 6;            // 0..3
    const int wm   = wave >> 1;         // 0..1 (row half)
    const int wn   = wave & 1;          // 0..1 (col half)
    const int fr   = lane & 15;
    const int fk   = lane >> 4;

    __shared__ unsigned short T[32][NROWS][68];   // bf16 bits, stride 68 (8B-aligned rows)
    __shared__ unsigned short combs[32][136];     // [dense 64 | Z 36 | pad]

    // ---- 1) GEMM2: 32x64, K=256, waves 2x2 -> per-wave 16 rows x 32 cols ----
    {
        facc4 acc[2] = {};
        const unsigned short* arow = h1b + (size_t)(r0 + wm * 16 + fr) * HIDDEN2;
        #pragma unroll
        for (int kw = 0; kw < 8; ++kw) {
            const bf16x8 af = *reinterpret_cast<const bf16x8*>(arow + kw * 32 + fk * 8);
            #pragma unroll
            for (int n = 0; n < 2; ++n) {
                const bf16x8 bw = *reinterpret_cast<const bf16x8*>(
                    w2b + (size_t)(wn * 32 + n * 16 + fr) * HIDDEN2 + kw * 32 + fk * 8);
                acc[n] = __builtin_amdgcn_mfma_f32_16x16x32_bf16(af, bw, acc[n], 0, 0, 0);
            }
        }
        #pragma unroll
        for (int n = 0; n < 2; ++n) {
            const int col = wn * 32 + n * 16 + fr;
            const float bv = b2[col];
            #pragma unroll
            for (int j = 0; j < 4; ++j) {
                const int row = wm * 16 + fk * 4 + j;
                const unsigned short hv = f2bf(acc[n][j] + bv);
                T[row][0][col]  = hv;
                combs[row][col] = hv;
            }
        }
    }

    // zero combs[.][100..135] (Wp pad region; avoid NaN*0)
    for (int p = t; p < 32 * 18; p += 256) {
        const int row = p / 18, c = p % 18;
        *reinterpret_cast<unsigned int*>(&combs[row][100 + c * 2]) = 0u;
    }

    // ---- 2) embeddings: 8 threads per row, 8 dims each ----
    {
        const int row = t >> 3;          // 0..31
        const int oc  = t & 7;           // dim octet
        const int br  = r0 + row;

        // features -> T[row][2..8]
        const int fbase = br * NFEAT;
        #pragma unroll
        for (int f = 0; f < NFEAT; ++f) {
            const int fi = feat_idx[fbase + f];
            const int q = fi / C_FEAT, r = fi - q * C_FEAT;
            const unsigned short* qp = qfb + ((size_t)f * NQ_FEAT + q) * EMB_D + oc * 8;
            const unsigned short* rp = rfb + ((size_t)f * C_FEAT  + r) * EMB_D + oc * 8;
            const uint2 qa = *reinterpret_cast<const uint2*>(qp);
            const uint2 qb = *reinterpret_cast<const uint2*>(qp + 4);
            const uint2 ra = *reinterpret_cast<const uint2*>(rp);
            const uint2 rb = *reinterpret_cast<const uint2*>(rp + 4);
            union { ushort8 v; uint2 u[2]; } pk;
            pk.v[0] = f2bf(blo(qa.x) * blo(ra.x));
            pk.v[1] = f2bf(bhi(qa.x) * bhi(ra.x));
            pk.v[2] = f2bf(blo(qa.y) * blo(ra.y));
            pk.v[3] = f2bf(bhi(qa.y) * bhi(ra.y));
            pk.v[4] = f2bf(blo(qb.x) * blo(rb.x));
            pk.v[5] = f2bf(bhi(qb.x) * bhi(rb.x));
            pk.v[6] = f2bf(blo(qb.y) * blo(rb.y));
            pk.v[7] = f2bf(bhi(qb.y) * bhi(rb.y));
            *reinterpret_cast<uint2*>(&T[row][2 + f][oc * 8])     = pk.u[0];
            *reinterpret_cast<uint2*>(&T[row][2 + f][oc * 8 + 4]) = pk.u[1];
        }

        // hist segment mean -> T[row][1]
        const int start = hist_off[br];
        const int end   = (br + 1 < B) ? hist_off[br + 1] : Mtot;
        const int cnt   = end - start;
        const int* hp = hist_idx + start;
        float a[8] = {};
        #pragma unroll 2
        for (int i = 0; i < cnt; ++i) {
            const int hi = hp[i];
            const int q = hi / C_CAMP, r = hi - q * C_CAMP;
            const unsigned short* qp = qcb + (size_t)q * EMB_D + oc * 8;
            const unsigned short* rp = rcb + (size_t)r * EMB_D + oc * 8;
            const uint2 qa = *reinterpret_cast<const uint2*>(qp);
            const uint2 qb = *reinterpret_cast<const uint2*>(qp + 4);
            const uint2 ra = *reinterpret_cast<const uint2*>(rp);
            const uint2 rb = *reinterpret_cast<const uint2*>(rp + 4);
            a[0] += blo(qa.x) * blo(ra.x); a[1] += bhi(qa.x) * bhi(ra.x);
            a[2] += blo(qa.y) * blo(ra.y); a[3] += bhi(qa.y) * bhi(ra.y);
            a[4] += blo(qb.x) * blo(rb.x); a[5] += bhi(qb.x) * bhi(rb.x);
            a[6] += blo(qb.y) * blo(rb.y); a[7] += bhi(qb.y) * bhi(rb.y);
        }
        const float inv = 1.f / (float)max(cnt, 1);
        union { ushort8 v; uint2 u[2]; } pk;
        #pragma unroll
        for (int k = 0; k < 8; ++k) pk.v[k] = f2bf(a[k] * inv);
        *reinterpret_cast<uint2*>(&T[row][1][oc * 8])     = pk.u[0];
        *reinterpret_cast<uint2*>(&T[row][1][oc * 8 + 4]) = pk.u[1];
    }
    __syncthreads();

    // ---- 3) interactions: 36 pairs x 32 rows ----
    for (int p = t; p < NPAIRS * 32; p += 256) {
        const int row = p & 31;
        const int pr  = p >> 5;
        int i = 0, rem = pr;
        while (rem >= (NROWS - 1) - i) { rem -= (NROWS - 1) - i; ++i; }
        const int j = i + 1 + rem;
        const unsigned short* ti = &T[row][i][0];
        const unsigned short* tj = &T[row][j][0];
        float s = 0.f;
        #pragma unroll
        for (int d = 0; d < EMB_D; d += 4) {
            const uint2 u = *reinterpret_cast<const uint2*>(ti + d);
            const uint2 v = *reinterpret_cast<const uint2*>(tj + d);
            s += blo(u.x) * blo(v.x) + bhi(u.x) * bhi(v.x)
               + blo(u.y) * blo(v.y) + bhi(u.y) * bhi(v.y);
        }
        combs[row][EMB_D + pr] = f2bf(s);
    }
    __syncthreads();

    // ---- 4) proj: 32x128 = combs[32x128] @ Wp^T, waves 2x2 -> 16 rows x 64 cols ----
    {
        facc4 acc[4] = {};
        #pragma unroll
        for (int kw = 0; kw < 4; ++kw) {
            const bf16x8 af = *reinterpret_cast<const bf16x8*>(
                &combs[wm * 16 + fr][kw * 32 + fk * 8]);
            #pragma unroll
            for (int n = 0; n < 4; ++n) {
                const bf16x8 bw = *reinterpret_cast<const bf16x8*>(
                    wpb + (size_t)(wn * 64 + n * 16 + fr) * KPROJ + kw * 32 + fk * 8);
                acc[n] = __builtin_amdgcn_mfma_f32_16x16x32_bf16(af, bw, acc[n], 0, 0, 0);
            }
        }
        #pragma unroll
        for (int n = 0; n < 4; ++n) {
            const int col = wn * 64 + n * 16 + fr;
            const float bv = bp[col];
            #pragma unroll
            for (int j = 0; j < 4; ++j) {
                const int row = wm * 16 + fk * 4 + j;
                out[(size_t)(r0 + row) * PROJ + col] = acc[n][j] + bv;
            }
        }
    }
}

// ---------------------------------------------------------------------------
extern "C" void kernel_launch(void* const* d_in, const int* in_sizes, int n_in,
                              void* d_out, int out_size, void* d_ws, size_t ws_size,
                              hipStream_t stream)
{
    const float* x        = (const float*)d_in[0];
    const int*   hist_idx = (const int*)  d_in[1];
    const int*   hist_off = (const int*)  d_in[2];
    const int*   feat_idx = (const int*)  d_in[3];
    const float* Wq_c     = (const float*)d_in[4];
    const float* Wr_c     = (const float*)d_in[5];
    const float* Wq_f     = (const float*)d_in[6];
    const float* Wr_f     = (const float*)d_in[7];
    const float* W0       = (const float*)d_in[8];
    const float* b0       = (const float*)d_in[9];
    const float* W1       = (const float*)d_in[10];
    const float* b1       = (const float*)d_in[11];
    const float* W2       = (const float*)d_in[12];
    const float* b2       = (const float*)d_in[13];
    const float* Wp       = (const float*)d_in[14];
    const float* bp       = (const float*)d_in[15];

    const int M    = in_sizes[0] / DENSE_D;   // 16384
    const int Mtot = in_sizes[1];             // B*HIST

    char* w = (char*)d_ws;
    auto take = [&](size_t bytes) { char* p = w; w += (bytes + 255) & ~(size_t)255; return p; };
    unsigned short* w0b = (unsigned short*)take(HIDDEN1 * DENSE_D * 2);
    unsigned short* w1b = (unsigned short*)take(HIDDEN2 * HIDDEN1 * 2);
    unsigned short* w2b = (unsigned short*)take(EMB_D * HIDDEN2 * 2);
    unsigned short* wpb = (unsigned short*)take(PROJ * KPROJ * 2);
    unsigned short* qcb = (unsigned short*)take(C_CAMP * EMB_D * 2);
    unsigned short* rcb = (unsigned short*)take(C_CAMP * EMB_D * 2);
    unsigned short* qfb = (unsigned short*)take(NFEAT * NQ_FEAT * EMB_D * 2);
    unsigned short* rfb = (unsigned short*)take(NFEAT * C_FEAT * EMB_D * 2);
    unsigned short* h0b = (unsigned short*)take((size_t)M * HIDDEN1 * 2);
    unsigned short* h1b = (unsigned short*)take((size_t)M * HIDDEN2 * 2);

    prep_all<<<512, 256, 0, stream>>>(W0, W1, W2, Wp, Wq_c, Wr_c, Wq_f, Wr_f,
                                      w0b, w1b, w2b, wpb, qcb, rcb, qfb, rfb);

    // x fp32 (reg-cast staging), 128x256 tile, 8 waves: grid 128x2 = 256 blocks
    gemm_bf16<128, 256, 2, 4, true, true, true>
        <<<dim3(M / 128, HIDDEN1 / 256), 512, 0, stream>>>(
        x, (const __hip_bfloat16*)w0b, b0, h0b, M, HIDDEN1, DENSE_D);

    // h0 bf16 (GLD), 64x256 tile: grid 256x1 = 256 blocks
    gemm_bf16<64, 256, 2, 4, true, true, false>
        <<<dim3(M / 64, HIDDEN2 / 256), 512, 0, stream>>>(
        h0b, (const __hip_bfloat16*)w1b, b1, h1b, M, HIDDEN2, HIDDEN1);

    // fused gemm2 + embed + interact + proj: 512 blocks x 32 rows
    tail_fused<<<M / 32, 256, 0, stream>>>(
        h1b, w2b, b2, hist_idx, hist_off, feat_idx,
        qcb, rcb, qfb, rfb, wpb, bp, (float*)d_out, M, Mtot);
}